// Round 13
// baseline (11531.251 us; speedup 1.0000x reference)
//
#include <hip/hip_runtime.h>

// ---------------------------------------------------------------------------
// Persistent 2-layer GRU, MI355X (gfx950).  B=128, T=1024, D=H=512.
// R10-proven dataflow at 2 wgs/CU: 512 wgs x 256 thr, role = (layer, mt, nt)
// = 16 batch rows x 16 hidden cols (3 gate frags). The 8 per-mt groups are
// independent recurrent chains; co-resident wgs overlap each other's MALL/
// poll stalls via hardware wave scheduling (the R11/R12 hand-pipeline goal,
// with zero new sync structure -- those faulted and are abandoned).
// Exchange: agent-scope sc1 stores/loads (MALL), per-wg seq words, vector
// poll; all waits vmcnt(0) (R9 lesson: no counted waits). Poll-iteration
// probe kept (1 deliberate bank-conflict ds_read per iter).
// __launch_bounds__(256,2) forces VGPR<=256 -> 2 waves/SIMD -> 2 wgs/CU.
// ---------------------------------------------------------------------------

#define TS   1024
#define HID  512
#define NWG  512
#define WGT  256

typedef __attribute__((ext_vector_type(8))) short bf16x8;
typedef __attribute__((ext_vector_type(4))) unsigned short u16x4;
typedef __attribute__((ext_vector_type(4))) float f32x4;

#define WS_FIN      4096
#define WS_HBUF     8192
#define HBUF_ELEMS  65536                             // 128*512 bf16 per buffer
#define WS_H1F      (WS_HBUF + 8 * HBUF_ELEMS * 2)    // fp32 [128][512]
#define WS_ZERO     (WS_HBUF + 8 * HBUF_ELEMS * 2)

__device__ __forceinline__ unsigned short f2bf(float f) {
    unsigned u = __float_as_uint(f);
    u += 0x7FFFu + ((u >> 16) & 1u);
    return (unsigned short)(u >> 16);
}
__device__ __forceinline__ float bf2f(unsigned short s) {
    return __uint_as_float(((unsigned)s) << 16);
}
__device__ __forceinline__ float sigm(float v) { return 1.0f / (1.0f + __expf(-v)); }
__device__ __forceinline__ float tanh_(float v) { return 1.0f - 2.0f / (1.0f + __expf(2.0f * v)); }

// agent-scope (MALL) ops — R8-proven
__device__ __forceinline__ void st_agent8(void* p, unsigned long long v) {
    asm volatile("global_store_dwordx2 %0, %1, off sc1" :: "v"(p), "v"(v) : "memory");
}
__device__ __forceinline__ void st_agent16(void* p, f32x4 v) {
    asm volatile("global_store_dwordx4 %0, %1, off sc1" :: "v"(p), "v"(v) : "memory");
}
__device__ __forceinline__ void ld_agent16_issue(bf16x8& d, const unsigned short* p) {
    asm volatile("global_load_dwordx4 %0, %1, off sc1" : "=v"(d) : "v"(p));
}
__device__ __forceinline__ void ld16_issue(f32x4& d, const float* p) {
    asm volatile("global_load_dwordx4 %0, %1, off" : "=v"(d) : "v"(p));
}
__device__ __forceinline__ void wait_vm0() {
    asm volatile("s_waitcnt vmcnt(0)" ::: "memory");
    __builtin_amdgcn_sched_barrier(0);
}
__device__ __forceinline__ f32x4 ld_coh16f(const float* p) {
    const unsigned long long* q = (const unsigned long long*)p;
    union { unsigned long long u[2]; f32x4 v; } r;
    r.u[0] = __hip_atomic_load(q,     __ATOMIC_RELAXED, __HIP_MEMORY_SCOPE_AGENT);
    r.u[1] = __hip_atomic_load(q + 1, __ATOMIC_RELAXED, __HIP_MEMORY_SCOPE_AGENT);
    return r.v;
}
__device__ __forceinline__ void splitPack2(float a, float b, unsigned& hiw, unsigned& low) {
    unsigned ba = __float_as_uint(a), bb = __float_as_uint(b);
    unsigned ha = ba & 0xFFFF0000u,   hb = bb & 0xFFFF0000u;
    float la = a - __uint_as_float(ha);
    float lb = b - __uint_as_float(hb);
    hiw = (ba >> 16) | hb;
    low = (__float_as_uint(la) >> 16) | (__float_as_uint(lb) & 0xFFFF0000u);
}

__global__ void __launch_bounds__(WGT, 2)
gru_persistent(const float* __restrict__ x,
               const float* __restrict__ wi0, const float* __restrict__ wh0,
               const float* __restrict__ bi0, const float* __restrict__ bh0,
               const float* __restrict__ wi1, const float* __restrict__ wh1,
               const float* __restrict__ bi1, const float* __restrict__ bh1,
               const float* __restrict__ fcw, const float* __restrict__ fcb,
               float* __restrict__ out, unsigned char* __restrict__ ws)
{
    __shared__ float ldsRed[3][64][25];        // 19200 B (reduce; FC reuse 16512B)

    const int tid   = threadIdx.x;
    const int lane  = tid & 63;
    const int kq    = tid >> 6;                // wave id = k-quarter
    const int wgid  = blockIdx.x;
    const int layer = wgid >> 8;               // 0 / 1
    const int wid   = wgid & 255;
    const int mt    = wid & 7;                 // 16-row m-tile (barrier group)
    const int nt    = wid >> 3;                // 16-col hidden tile, 0..31
    const int l15   = lane & 15;
    const int l4    = lane >> 4;
    const int gidx  = layer * 32 + nt;         // slot 0..63 within mt-group

    unsigned* seqA = (unsigned*)(ws + (size_t)mt * 256);
    unsigned* fin  = (unsigned*)(ws + WS_FIN);
    unsigned short* hbm = (unsigned short*)(ws + WS_HBUF);
    float* h1f = (float*)(ws + WS_H1F);

    unsigned short* h0hi[2] = { hbm + 0 * HBUF_ELEMS, hbm + 1 * HBUF_ELEMS };
    unsigned short* h0lo[2] = { hbm + 2 * HBUF_ELEMS, hbm + 3 * HBUF_ELEMS };
    unsigned short* h1hi[2] = { hbm + 4 * HBUF_ELEMS, hbm + 5 * HBUF_ELEMS };
    unsigned short* h1lo[2] = { hbm + 6 * HBUF_ELEMS, hbm + 7 * HBUF_ELEMS };

    // ---- stage weight fragments into REGISTERS (fp32 -> bf16) ----
    bf16x8 wiR[4][3], whR[4][3];
    {
        const float* Wi = layer ? wi1 : wi0;
        const float* Wh = layer ? wh1 : wh0;
        #pragma unroll
        for (int kk = 0; kk < 4; ++kk) {
            const int kc = (kq << 2) + kk;
            #pragma unroll
            for (int g = 0; g < 3; ++g) {
                const int jg = g * HID + nt * 16 + l15;
                const float* pi = Wi + (size_t)jg * HID + kc * 32 + (l4 << 3);
                const float* ph = Wh + (size_t)jg * HID + kc * 32 + (l4 << 3);
                #pragma unroll
                for (int e = 0; e < 8; ++e) {
                    wiR[kk][g][e] = (short)f2bf(pi[e]);
                    whR[kk][g][e] = (short)f2bf(ph[e]);
                }
            }
        }
    }

    // ---- per-thread biases (wave 0 only): col j = nt*16 + l4*4 + r ----
    float br[4], bz[4], bni[4], bnh[4];
    if (kq == 0) {
        const float* Bi = layer ? bi1 : bi0;
        const float* Bh = layer ? bh1 : bh0;
        #pragma unroll
        for (int r = 0; r < 4; ++r) {
            int j = nt * 16 + (l4 << 2) + r;
            br[r]  = Bi[j] + Bh[j];
            bz[r]  = Bi[HID + j] + Bh[HID + j];
            bni[r] = Bi[2 * HID + j];
            bnh[r] = Bh[2 * HID + j];
        }
    } else {
        #pragma unroll
        for (int r = 0; r < 4; ++r) br[r] = bz[r] = bni[r] = bnh[r] = 0.f;
    }

    float hold[4] = {0,0,0,0};
    f32x4 acc_i[3], acc_h[3];
    #pragma unroll
    for (int g = 0; g < 3; ++g) {
        acc_i[g] = (f32x4){0.f,0.f,0.f,0.f};
        acc_h[g] = (f32x4){0.f,0.f,0.f,0.f};
    }

    f32x4 xs[4][2];                            // x stash for step s+1 (L0)

    // window x-GEMM from stashed registers: zero acc_i, split, 24 MFMAs
    auto do_window = [&]() {
        #pragma unroll
        for (int g = 0; g < 3; ++g) acc_i[g] = (f32x4){0.f,0.f,0.f,0.f};
        #pragma unroll
        for (int kk = 0; kk < 4; ++kk) {
            union { unsigned u[4]; bf16x8 v; } hi, lo;
            splitPack2(xs[kk][0][0], xs[kk][0][1], hi.u[0], lo.u[0]);
            splitPack2(xs[kk][0][2], xs[kk][0][3], hi.u[1], lo.u[1]);
            splitPack2(xs[kk][1][0], xs[kk][1][1], hi.u[2], lo.u[2]);
            splitPack2(xs[kk][1][2], xs[kk][1][3], hi.u[3], lo.u[3]);
            #pragma unroll
            for (int g = 0; g < 3; ++g) {
                acc_i[g] = __builtin_amdgcn_mfma_f32_16x16x32_bf16(wiR[kk][g], lo.v, acc_i[g], 0, 0, 0);
                acc_i[g] = __builtin_amdgcn_mfma_f32_16x16x32_bf16(wiR[kk][g], hi.v, acc_i[g], 0, 0, 0);
            }
        }
    };

    // ---- prologue: x-GEMM for step 0 (L0) ----
    if (layer == 0) {
        #pragma unroll
        for (int kk = 0; kk < 4; ++kk) {
            const int m = mt * 16 + l15;
            const int k = ((kq << 2) + kk) * 32 + (l4 << 3);
            const float* xp = x + ((size_t)m * TS + 0) * HID + k;
            ld16_issue(xs[kk][0], xp);
            ld16_issue(xs[kk][1], xp + 4);
        }
        wait_vm0();
        do_window();
    }

    for (int s = 0; s <= TS; ++s) {
        const int wp = s & 1, rp = wp ^ 1;
        const bool active = layer ? (s >= 1) : (s < TS);
        const bool window = (layer == 0) && (s + 1 < TS);
        if (active) {
            #pragma unroll
            for (int g = 0; g < 3; ++g) {
                acc_h[g] = (f32x4){0.f,0.f,0.f,0.f};
                if (layer) acc_i[g] = (f32x4){0.f,0.f,0.f,0.f};
            }

            const unsigned short* pIhi = h0hi[rp];
            const unsigned short* pIlo = h0lo[rp];
            const unsigned short* pHhi = layer ? h1hi[rp] : h0hi[rp];
            const unsigned short* pHlo = layer ? h1lo[rp] : h0lo[rp];

            // ---- batched issue: all h agent loads (+ x stash) ----
            bf16x8 hH[4][2], hI[4][2];
            #pragma unroll
            for (int kk = 0; kk < 4; ++kk) {
                const int fo = (((mt * 16 + (kq << 2) + kk) * 64) + lane) * 8;
                ld_agent16_issue(hH[kk][0], pHhi + fo);
                ld_agent16_issue(hH[kk][1], pHlo + fo);
                if (layer) {
                    ld_agent16_issue(hI[kk][0], pIhi + fo);
                    ld_agent16_issue(hI[kk][1], pIlo + fo);
                }
            }
            if (window) {
                #pragma unroll
                for (int kk = 0; kk < 4; ++kk) {
                    const int m = mt * 16 + l15;
                    const int k = ((kq << 2) + kk) * 32 + (l4 << 3);
                    const float* xp = x + ((size_t)m * TS + (s + 1)) * HID + k;
                    ld16_issue(xs[kk][0], xp);
                    ld16_issue(xs[kk][1], xp + 4);
                }
            }
            wait_vm0();

            // ---- MFMAs (all operands in registers) ----
            #pragma unroll
            for (int kk = 0; kk < 4; ++kk) {
                if (layer) {
                    #pragma unroll
                    for (int g = 0; g < 3; ++g) {
                        acc_i[g] = __builtin_amdgcn_mfma_f32_16x16x32_bf16(wiR[kk][g], hI[kk][1], acc_i[g], 0, 0, 0);
                        acc_i[g] = __builtin_amdgcn_mfma_f32_16x16x32_bf16(wiR[kk][g], hI[kk][0], acc_i[g], 0, 0, 0);
                    }
                }
                #pragma unroll
                for (int g = 0; g < 3; ++g) {
                    acc_h[g] = __builtin_amdgcn_mfma_f32_16x16x32_bf16(whR[kk][g], hH[kk][1], acc_h[g], 0, 0, 0);
                    acc_h[g] = __builtin_amdgcn_mfma_f32_16x16x32_bf16(whR[kk][g], hH[kk][0], acc_h[g], 0, 0, 0);
                }
            }

            // ---- k-split reduction ----
            if (kq != 0) {
                float* p = &ldsRed[kq - 1][lane][0];
                #pragma unroll
                for (int g = 0; g < 3; ++g) {
                    *(f32x4*)(p + g * 4)      = acc_i[g];
                    *(f32x4*)(p + 12 + g * 4) = acc_h[g];
                }
            }
            __syncthreads();                   // (A)
            if (kq == 0) {
                #pragma unroll
                for (int q = 0; q < 3; ++q) {
                    const float* p = &ldsRed[q][lane][0];
                    #pragma unroll
                    for (int g = 0; g < 3; ++g) {
                        acc_i[g] += *(const f32x4*)(p + g * 4);
                        acc_h[g] += *(const f32x4*)(p + 12 + g * 4);
                    }
                }
                // ---- gates (fp32) + fragment-layout hi/lo store ----
                unsigned short* dsthi = layer ? h1hi[wp] : h0hi[wp];
                unsigned short* dstlo = layer ? h1lo[wp] : h0lo[wp];
                u16x4 shi, slo; f32x4 hv;
                #pragma unroll
                for (int r = 0; r < 4; ++r) {
                    float vr = acc_i[0][r] + acc_h[0][r] + br[r];
                    float vz = acc_i[1][r] + acc_h[1][r] + bz[r];
                    float rg = sigm(vr);
                    float zg = sigm(vz);
                    float ng = tanh_(acc_i[2][r] + bni[r] + rg * (acc_h[2][r] + bnh[r]));
                    float h  = (1.0f - zg) * ng + zg * hold[r];
                    hold[r] = h; hv[r] = h;
                    unsigned short hb = f2bf(h);
                    shi[r] = hb;
                    slo[r] = f2bf(h - bf2f(hb));
                }
                // (row l15, cols nt*16 + l4*4 + r) -> chunk nt>>1, subcol nt&1
                const int lanep = l15 + ((((nt & 1) << 1) + (l4 >> 1)) << 4);
                const int eo = (((mt * 16 + (nt >> 1)) * 64) + lanep) * 8 + (l4 & 1) * 4;
                st_agent8(dsthi + eo, __builtin_bit_cast(unsigned long long, shi));
                st_agent8(dstlo + eo, __builtin_bit_cast(unsigned long long, slo));
                if (layer && s == TS) {
                    const int m = mt * 16 + l15;
                    st_agent16(h1f + (size_t)m * HID + nt * 16 + (l4 << 2), hv);
                }
            }
        }

        // ---- arrive: drain stores (ACKed at MALL), publish seq ----
        if (tid == 0) {
            asm volatile("s_waitcnt vmcnt(0)" ::: "memory");
            __hip_atomic_store(&seqA[gidx], (unsigned)(s + 1),
                               __ATOMIC_RELAXED, __HIP_MEMORY_SCOPE_AGENT);
        }

        // ---- barrier window: L0 computes next step's x-GEMM (reg-only) ----
        if (window) do_window();

        // ---- poll: all 64 group seqs >= s+1  (+ iteration probe) ----
        if (kq == 0) {
            const unsigned tgt = (unsigned)(s + 1);
            const int paddr = lane << 8;       // 64 lanes -> bank 0, max 16128 < 19200
            for (;;) {
                unsigned probe;
                asm volatile("ds_read_b32 %0, %1\n\ts_waitcnt lgkmcnt(0)"
                             : "=v"(probe) : "v"(paddr));
                bool ok = true;
                if (lane < 16) {
                    const unsigned long long* sp =
                        (const unsigned long long*)(seqA + (lane << 2));
                    unsigned long long a = __hip_atomic_load(sp,     __ATOMIC_RELAXED, __HIP_MEMORY_SCOPE_AGENT);
                    unsigned long long b = __hip_atomic_load(sp + 1, __ATOMIC_RELAXED, __HIP_MEMORY_SCOPE_AGENT);
                    ok = ((unsigned)a >= tgt) && ((unsigned)(a >> 32) >= tgt) &&
                         ((unsigned)b >= tgt) && ((unsigned)(b >> 32) >= tgt);
                }
                if (__all(ok)) break;
                __builtin_amdgcn_s_sleep(1);
            }
        }
        __syncthreads();                       // (B)
    }

    // ---- global fin barrier (one-shot), then FC epilogue ----
    if (tid == 0) {
        asm volatile("s_waitcnt vmcnt(0)" ::: "memory");
        __hip_atomic_fetch_add(fin, 1u, __ATOMIC_RELAXED, __HIP_MEMORY_SCOPE_AGENT);
    }
    if (wgid < 64) {
        float* fw = &ldsRed[0][0][0];             // 8 rows x 516 floats = 16512 B
        const float* src = fcw + (size_t)wgid * 8 * HID;
        for (int i = tid; i < (8 * HID) / 4; i += WGT) {
            f32x4 v = *(const f32x4*)(src + i * 4);
            int row = (i * 4) >> 9;
            int kk  = (i * 4) & 511;
            *(f32x4*)(fw + row * 516 + kk) = v;
        }
        if (tid == 0) {
            while (__hip_atomic_load(fin, __ATOMIC_RELAXED, __HIP_MEMORY_SCOPE_AGENT) < (unsigned)NWG)
                __builtin_amdgcn_s_sleep(1);
        }
        __syncthreads();
        const int col = wgid * 8 + (tid & 7);
        const int m0  = tid >> 3;
        float a0 = fcb[col], a1 = a0, a2 = a0, a3 = a0;
        const float* fwr = fw + (tid & 7) * 516;
        for (int k = 0; k < HID; k += 4) {
            f32x4 wv  = *(const f32x4*)(fwr + k);
            f32x4 h0v = ld_coh16f(h1f + (size_t)(m0)      * HID + k);
            f32x4 h1v = ld_coh16f(h1f + (size_t)(m0 + 32) * HID + k);
            f32x4 h2v = ld_coh16f(h1f + (size_t)(m0 + 64) * HID + k);
            f32x4 h3v = ld_coh16f(h1f + (size_t)(m0 + 96) * HID + k);
            a0 += h0v[0]*wv[0] + h0v[1]*wv[1] + h0v[2]*wv[2] + h0v[3]*wv[3];
            a1 += h1v[0]*wv[0] + h1v[1]*wv[1] + h1v[2]*wv[2] + h1v[3]*wv[3];
            a2 += h2v[0]*wv[0] + h2v[1]*wv[1] + h2v[2]*wv[2] + h2v[3]*wv[3];
            a3 += h3v[0]*wv[0] + h3v[1]*wv[1] + h3v[2]*wv[2] + h3v[3]*wv[3];
        }
        out[(size_t)(m0)      * HID + col] = a0;
        out[(size_t)(m0 + 32) * HID + col] = a1;
        out[(size_t)(m0 + 64) * HID + col] = a2;
        out[(size_t)(m0 + 96) * HID + col] = a3;
    }
}

extern "C" void kernel_launch(void* const* d_in, const int* in_sizes, int n_in,
                              void* d_out, int out_size, void* d_ws, size_t ws_size,
                              hipStream_t stream) {
    (void)in_sizes; (void)n_in; (void)out_size; (void)ws_size;
    hipMemsetAsync(d_ws, 0, WS_ZERO, stream);
    gru_persistent<<<dim3(NWG), dim3(WGT), 0, stream>>>(
        (const float*)d_in[0],
        (const float*)d_in[1], (const float*)d_in[2],
        (const float*)d_in[3], (const float*)d_in[4],
        (const float*)d_in[5], (const float*)d_in[6],
        (const float*)d_in[7], (const float*)d_in[8],
        (const float*)d_in[9], (const float*)d_in[10],
        (float*)d_out, (unsigned char*)d_ws);
}

// Round 14
// 7360.370 us; speedup vs baseline: 1.5667x; 1.5667x over previous
//
#include <hip/hip_runtime.h>

// ---------------------------------------------------------------------------
// Persistent 2-layer GRU, MI355X (gfx950).  B=128, T=1024, D=H=512.
// R10-proven structure (256 wgs x 256 thr, (layer, mtile, ntile) = 16 rows x
// 32 cols, k-split 4x128, weights in registers, agent-scope sc1 h exchange
// via MALL, per-wg seq words + vector poll, vmcnt(0)-only waits, poll probe).
// CHANGE vs R10: h transmitted as 1-TERM bf16 (hi only; lo dropped).
// Rationale: absmax 1.95e-3 vs threshold 6.76e-3 (3.5x margin); weight
// rounding (2^-8) dominates; recurrence contracts noise. Halves h-load
// burst (16->8 loads L1, 16->12 L0), h stores (2->1 per n2), h MFMAs.
// x keeps the 2-term hi/lo split (off critical path). h_old stays exact
// fp32 in registers; only the transmitted operand is rounded.
// ---------------------------------------------------------------------------

#define TS   1024
#define HID  512
#define NWG  256
#define WGT  256

typedef __attribute__((ext_vector_type(8))) short bf16x8;
typedef __attribute__((ext_vector_type(4))) unsigned short u16x4;
typedef __attribute__((ext_vector_type(4))) float f32x4;

#define WS_FIN      2048
#define WS_HBUF     8192
#define HBUF_ELEMS  65536                             // 128*512 bf16 per buffer
#define WS_H1F      (WS_HBUF + 8 * HBUF_ELEMS * 2)    // fp32 [128][512]
#define WS_ZERO     (WS_HBUF + 8 * HBUF_ELEMS * 2)

__device__ __forceinline__ unsigned short f2bf(float f) {
    unsigned u = __float_as_uint(f);
    u += 0x7FFFu + ((u >> 16) & 1u);
    return (unsigned short)(u >> 16);
}
__device__ __forceinline__ float bf2f(unsigned short s) {
    return __uint_as_float(((unsigned)s) << 16);
}
__device__ __forceinline__ float sigm(float v) { return 1.0f / (1.0f + __expf(-v)); }
__device__ __forceinline__ float tanh_(float v) { return 1.0f - 2.0f / (1.0f + __expf(2.0f * v)); }

// agent-scope (MALL) ops
__device__ __forceinline__ void st_agent8(void* p, unsigned long long v) {
    asm volatile("global_store_dwordx2 %0, %1, off sc1" :: "v"(p), "v"(v) : "memory");
}
__device__ __forceinline__ void st_agent16(void* p, f32x4 v) {
    asm volatile("global_store_dwordx4 %0, %1, off sc1" :: "v"(p), "v"(v) : "memory");
}
__device__ __forceinline__ void ld_agent16_issue(bf16x8& d, const unsigned short* p) {
    asm volatile("global_load_dwordx4 %0, %1, off sc1" : "=v"(d) : "v"(p));
}
// plain cached load (x input), issue-only
__device__ __forceinline__ void ld16_issue(f32x4& d, const float* p) {
    asm volatile("global_load_dwordx4 %0, %1, off" : "=v"(d) : "v"(p));
}
__device__ __forceinline__ void wait_vm0() {
    asm volatile("s_waitcnt vmcnt(0)" ::: "memory");
    __builtin_amdgcn_sched_barrier(0);
}
// coherent fp32x4 load (FC epilogue only)
__device__ __forceinline__ f32x4 ld_coh16f(const float* p) {
    const unsigned long long* q = (const unsigned long long*)p;
    union { unsigned long long u[2]; f32x4 v; } r;
    r.u[0] = __hip_atomic_load(q,     __ATOMIC_RELAXED, __HIP_MEMORY_SCOPE_AGENT);
    r.u[1] = __hip_atomic_load(q + 1, __ATOMIC_RELAXED, __HIP_MEMORY_SCOPE_AGENT);
    return r.v;
}
__device__ __forceinline__ void splitPack2(float a, float b, unsigned& hiw, unsigned& low) {
    unsigned ba = __float_as_uint(a), bb = __float_as_uint(b);
    unsigned ha = ba & 0xFFFF0000u,   hb = bb & 0xFFFF0000u;
    float la = a - __uint_as_float(ha);
    float lb = b - __uint_as_float(hb);
    hiw = (ba >> 16) | hb;
    low = (__float_as_uint(la) >> 16) | (__float_as_uint(lb) & 0xFFFF0000u);
}

__global__ void __launch_bounds__(WGT, 1)
gru_persistent(const float* __restrict__ x,
               const float* __restrict__ wi0, const float* __restrict__ wh0,
               const float* __restrict__ bi0, const float* __restrict__ bh0,
               const float* __restrict__ wi1, const float* __restrict__ wh1,
               const float* __restrict__ bi1, const float* __restrict__ bh1,
               const float* __restrict__ fcw, const float* __restrict__ fcb,
               float* __restrict__ out, unsigned char* __restrict__ ws)
{
    __shared__ float ldsRed[3][64][49];        // 37632 B k-split partials

    const int tid   = threadIdx.x;
    const int lane  = tid & 63;
    const int kq    = tid >> 6;                // wave id = k-quarter
    const int wgid  = blockIdx.x;
    const int layer = wgid >> 7;
    const int wid   = wgid & 127;
    const int mtile = wid & 7;                 // 16-row m-tile (barrier group)
    const int ntile = wid >> 3;                // 32-col hidden tile
    const int l15   = lane & 15;
    const int l4    = lane >> 4;
    const int gidx  = layer * 16 + ntile;      // 0..31 within mtile-group

    unsigned* seqA = (unsigned*)(ws + (size_t)mtile * 256);
    unsigned* fin  = (unsigned*)(ws + WS_FIN);
    unsigned short* hbm = (unsigned short*)(ws + WS_HBUF);
    float* h1f = (float*)(ws + WS_H1F);

    // 1-term h: only hi buffers used (lo region left idle)
    unsigned short* h0hi[2] = { hbm + 0 * HBUF_ELEMS, hbm + 1 * HBUF_ELEMS };
    unsigned short* h1hi[2] = { hbm + 4 * HBUF_ELEMS, hbm + 5 * HBUF_ELEMS };

    // ---- stage weight fragments into REGISTERS (fp32 -> bf16) ----
    bf16x8 wiR[4][6], whR[4][6];
    {
        const float* Wi = layer ? wi1 : wi0;
        const float* Wh = layer ? wh1 : wh0;
        #pragma unroll
        for (int kk = 0; kk < 4; ++kk) {
            const int kc = (kq << 2) + kk;
            #pragma unroll
            for (int f = 0; f < 6; ++f) {
                const int g = f >> 1, n2 = f & 1;
                const int jg = g * HID + ntile * 32 + n2 * 16 + l15;
                const float* pi = Wi + (size_t)jg * HID + kc * 32 + (l4 << 3);
                const float* ph = Wh + (size_t)jg * HID + kc * 32 + (l4 << 3);
                #pragma unroll
                for (int e = 0; e < 8; ++e) {
                    wiR[kk][f][e] = (short)f2bf(pi[e]);
                    whR[kk][f][e] = (short)f2bf(ph[e]);
                }
            }
        }
    }

    // ---- per-thread biases (wave 0 only) ----
    float br[2][4], bz[2][4], bni[2][4], bnh[2][4];
    if (kq == 0) {
        const float* Bi = layer ? bi1 : bi0;
        const float* Bh = layer ? bh1 : bh0;
        #pragma unroll
        for (int n2 = 0; n2 < 2; ++n2)
            #pragma unroll
            for (int r = 0; r < 4; ++r) {
                int j = ntile * 32 + n2 * 16 + (l4 << 2) + r;
                br[n2][r]  = Bi[j] + Bh[j];
                bz[n2][r]  = Bi[HID + j] + Bh[HID + j];
                bni[n2][r] = Bi[2 * HID + j];
                bnh[n2][r] = Bh[2 * HID + j];
            }
    } else {
        #pragma unroll
        for (int n2 = 0; n2 < 2; ++n2)
            #pragma unroll
            for (int r = 0; r < 4; ++r)
                br[n2][r] = bz[n2][r] = bni[n2][r] = bnh[n2][r] = 0.f;
    }

    float hold[2][4] = {{0,0,0,0},{0,0,0,0}};
    f32x4 acc_i[6], acc_h[6];
    #pragma unroll
    for (int f = 0; f < 6; ++f) {
        acc_i[f] = (f32x4){0.f,0.f,0.f,0.f};
        acc_h[f] = (f32x4){0.f,0.f,0.f,0.f};
    }

    f32x4 xs[4][2];                            // x stash for step s+1 (L0)

    // window x-GEMM from stashed registers (2-term x, 48 MFMAs)
    auto do_window = [&]() {
        #pragma unroll
        for (int f = 0; f < 6; ++f) acc_i[f] = (f32x4){0.f,0.f,0.f,0.f};
        #pragma unroll
        for (int kk = 0; kk < 4; ++kk) {
            union { unsigned u[4]; bf16x8 v; } hi, lo;
            splitPack2(xs[kk][0][0], xs[kk][0][1], hi.u[0], lo.u[0]);
            splitPack2(xs[kk][0][2], xs[kk][0][3], hi.u[1], lo.u[1]);
            splitPack2(xs[kk][1][0], xs[kk][1][1], hi.u[2], lo.u[2]);
            splitPack2(xs[kk][1][2], xs[kk][1][3], hi.u[3], lo.u[3]);
            #pragma unroll
            for (int f = 0; f < 6; ++f) {
                acc_i[f] = __builtin_amdgcn_mfma_f32_16x16x32_bf16(wiR[kk][f], lo.v, acc_i[f], 0, 0, 0);
                acc_i[f] = __builtin_amdgcn_mfma_f32_16x16x32_bf16(wiR[kk][f], hi.v, acc_i[f], 0, 0, 0);
            }
        }
    };

    // ---- prologue: x-GEMM for step 0 (L0) ----
    if (layer == 0) {
        #pragma unroll
        for (int kk = 0; kk < 4; ++kk) {
            const int m = mtile * 16 + l15;
            const int k = ((kq << 2) + kk) * 32 + (l4 << 3);
            const float* xp = x + ((size_t)m * TS + 0) * HID + k;
            ld16_issue(xs[kk][0], xp);
            ld16_issue(xs[kk][1], xp + 4);
        }
        wait_vm0();
        do_window();
    }

    for (int s = 0; s <= TS; ++s) {
        const int wp = s & 1, rp = wp ^ 1;
        const bool active = layer ? (s >= 1) : (s < TS);
        const bool window = (layer == 0) && (s + 1 < TS);
        if (active) {
            #pragma unroll
            for (int f = 0; f < 6; ++f) {
                acc_h[f] = (f32x4){0.f,0.f,0.f,0.f};
                if (layer) acc_i[f] = (f32x4){0.f,0.f,0.f,0.f};
            }

            const unsigned short* pIhi = h0hi[rp];
            const unsigned short* pHhi = layer ? h1hi[rp] : h0hi[rp];

            // ---- batched issue: 1-term h loads (+ x stash) ----
            bf16x8 hH[4], hI[4];
            #pragma unroll
            for (int kk = 0; kk < 4; ++kk) {
                const int fo = (((mtile * 16 + (kq << 2) + kk) * 64) + lane) * 8;
                ld_agent16_issue(hH[kk], pHhi + fo);
                if (layer) ld_agent16_issue(hI[kk], pIhi + fo);
            }
            if (window) {
                #pragma unroll
                for (int kk = 0; kk < 4; ++kk) {
                    const int m = mtile * 16 + l15;
                    const int k = ((kq << 2) + kk) * 32 + (l4 << 3);
                    const float* xp = x + ((size_t)m * TS + (s + 1)) * HID + k;
                    ld16_issue(xs[kk][0], xp);
                    ld16_issue(xs[kk][1], xp + 4);
                }
            }
            wait_vm0();

            // ---- MFMAs (1-term h) ----
            #pragma unroll
            for (int kk = 0; kk < 4; ++kk) {
                if (layer) {
                    #pragma unroll
                    for (int f = 0; f < 6; ++f)
                        acc_i[f] = __builtin_amdgcn_mfma_f32_16x16x32_bf16(wiR[kk][f], hI[kk], acc_i[f], 0, 0, 0);
                }
                #pragma unroll
                for (int f = 0; f < 6; ++f)
                    acc_h[f] = __builtin_amdgcn_mfma_f32_16x16x32_bf16(whR[kk][f], hH[kk], acc_h[f], 0, 0, 0);
            }

            // ---- k-split reduction ----
            if (kq != 0) {
                float* p = &ldsRed[kq - 1][lane][0];
                #pragma unroll
                for (int f = 0; f < 6; ++f) {
                    *(f32x4*)(p + f * 4)      = acc_i[f];
                    *(f32x4*)(p + 24 + f * 4) = acc_h[f];
                }
            }
            __syncthreads();                   // (A)
            if (kq == 0) {
                #pragma unroll
                for (int q = 0; q < 3; ++q) {
                    const float* p = &ldsRed[q][lane][0];
                    #pragma unroll
                    for (int f = 0; f < 6; ++f) {
                        acc_i[f] += *(const f32x4*)(p + f * 4);
                        acc_h[f] += *(const f32x4*)(p + 24 + f * 4);
                    }
                }
                // ---- gates (fp32) + fragment-layout 1-term store ----
                unsigned short* dsthi = layer ? h1hi[wp] : h0hi[wp];
                #pragma unroll
                for (int n2 = 0; n2 < 2; ++n2) {
                    u16x4 shi; f32x4 hv;
                    #pragma unroll
                    for (int r = 0; r < 4; ++r) {
                        float vr = acc_i[n2][r]     + acc_h[n2][r]     + br[n2][r];
                        float vz = acc_i[2 + n2][r] + acc_h[2 + n2][r] + bz[n2][r];
                        float rg = sigm(vr);
                        float zg = sigm(vz);
                        float ng = tanh_(acc_i[4 + n2][r] + bni[n2][r] + rg * (acc_h[4 + n2][r] + bnh[n2][r]));
                        float h  = (1.0f - zg) * ng + zg * hold[n2][r];
                        hold[n2][r] = h;
                        hv[r] = h;
                        shi[r] = f2bf(h);
                    }
                    const int eo = (((mtile * 16 + ntile) * 64) + l15 + (n2 * 2 + (l4 >> 1)) * 16) * 8
                                 + (l4 & 1) * 4;
                    st_agent8(dsthi + eo, __builtin_bit_cast(unsigned long long, shi));
                    if (layer && s == TS) {
                        const int m = mtile * 16 + l15;
                        st_agent16(h1f + (size_t)m * HID + ntile * 32 + n2 * 16 + (l4 << 2), hv);
                    }
                }
            }
        }

        // ---- arrive: drain stores (ACKed at MALL), publish seq ----
        if (tid == 0) {
            asm volatile("s_waitcnt vmcnt(0)" ::: "memory");
            __hip_atomic_store(&seqA[gidx], (unsigned)(s + 1),
                               __ATOMIC_RELAXED, __HIP_MEMORY_SCOPE_AGENT);
        }

        // ---- barrier window: L0 computes next step's x-GEMM (reg-only) ----
        if (window) do_window();

        // ---- poll: all 32 group seqs >= s+1  (+ iteration probe) ----
        if (kq == 0) {
            const unsigned tgt = (unsigned)(s + 1);
            const int paddr = lane << 9;       // probe: 64 lanes -> bank 0
            for (;;) {
                unsigned probe;
                asm volatile("ds_read_b32 %0, %1\n\ts_waitcnt lgkmcnt(0)"
                             : "=v"(probe) : "v"(paddr));
                bool ok = true;
                if (lane < 8) {
                    const unsigned long long* sp =
                        (const unsigned long long*)(seqA + ((lane & 7) << 2));
                    unsigned long long a = __hip_atomic_load(sp,     __ATOMIC_RELAXED, __HIP_MEMORY_SCOPE_AGENT);
                    unsigned long long b = __hip_atomic_load(sp + 1, __ATOMIC_RELAXED, __HIP_MEMORY_SCOPE_AGENT);
                    ok = ((unsigned)a >= tgt) && ((unsigned)(a >> 32) >= tgt) &&
                         ((unsigned)b >= tgt) && ((unsigned)(b >> 32) >= tgt);
                }
                if (__all(ok)) break;
                __builtin_amdgcn_s_sleep(1);
            }
        }
        __syncthreads();                       // (B)
    }

    // ---- global fin barrier (one-shot), then FC epilogue ----
    if (tid == 0) {
        asm volatile("s_waitcnt vmcnt(0)" ::: "memory");
        __hip_atomic_fetch_add(fin, 1u, __ATOMIC_RELAXED, __HIP_MEMORY_SCOPE_AGENT);
    }
    if (wgid < 64) {
        float* fw = &ldsRed[0][0][0];             // 8 rows x 516 floats
        const float* src = fcw + (size_t)wgid * 8 * HID;
        for (int i = tid; i < (8 * HID) / 4; i += WGT) {
            f32x4 v = *(const f32x4*)(src + i * 4);
            int row = (i * 4) >> 9;
            int kk  = (i * 4) & 511;
            *(f32x4*)(fw + row * 516 + kk) = v;
        }
        if (tid == 0) {
            while (__hip_atomic_load(fin, __ATOMIC_RELAXED, __HIP_MEMORY_SCOPE_AGENT) < (unsigned)NWG)
                __builtin_amdgcn_s_sleep(1);
        }
        __syncthreads();
        const int col = wgid * 8 + (tid & 7);
        const int m0  = tid >> 3;
        float a0 = fcb[col], a1 = a0, a2 = a0, a3 = a0;
        const float* fwr = fw + (tid & 7) * 516;
        for (int k = 0; k < HID; k += 4) {
            f32x4 wv  = *(const f32x4*)(fwr + k);
            f32x4 h0v = ld_coh16f(h1f + (size_t)(m0)      * HID + k);
            f32x4 h1v = ld_coh16f(h1f + (size_t)(m0 + 32) * HID + k);
            f32x4 h2v = ld_coh16f(h1f + (size_t)(m0 + 64) * HID + k);
            f32x4 h3v = ld_coh16f(h1f + (size_t)(m0 + 96) * HID + k);
            a0 += h0v[0]*wv[0] + h0v[1]*wv[1] + h0v[2]*wv[2] + h0v[3]*wv[3];
            a1 += h1v[0]*wv[0] + h1v[1]*wv[1] + h1v[2]*wv[2] + h1v[3]*wv[3];
            a2 += h2v[0]*wv[0] + h2v[1]*wv[1] + h2v[2]*wv[2] + h2v[3]*wv[3];
            a3 += h3v[0]*wv[0] + h3v[1]*wv[1] + h3v[2]*wv[2] + h3v[3]*wv[3];
        }
        out[(size_t)(m0)      * HID + col] = a0;
        out[(size_t)(m0 + 32) * HID + col] = a1;
        out[(size_t)(m0 + 64) * HID + col] = a2;
        out[(size_t)(m0 + 96) * HID + col] = a3;
    }
}

extern "C" void kernel_launch(void* const* d_in, const int* in_sizes, int n_in,
                              void* d_out, int out_size, void* d_ws, size_t ws_size,
                              hipStream_t stream) {
    (void)in_sizes; (void)n_in; (void)out_size; (void)ws_size;
    hipMemsetAsync(d_ws, 0, WS_ZERO, stream);
    gru_persistent<<<dim3(NWG), dim3(WGT), 0, stream>>>(
        (const float*)d_in[0],
        (const float*)d_in[1], (const float*)d_in[2],
        (const float*)d_in[3], (const float*)d_in[4],
        (const float*)d_in[5], (const float*)d_in[6],
        (const float*)d_in[7], (const float*)d_in[8],
        (const float*)d_in[9], (const float*)d_in[10],
        (float*)d_out, (unsigned char*)d_ws);
}